// Round 1
// 892.071 us; speedup vs baseline: 1.2173x; 1.2173x over previous
//
#include <hip/hip_runtime.h>
#include <hip/hip_bf16.h>

#define B_ 16
#define S_ 2048
#define D_ 512
#define M_ (B_ * S_)  // 32768 rows for the GEMMs

typedef __attribute__((ext_vector_type(8))) _Float16 f16x8;
typedef __attribute__((ext_vector_type(4))) float f32x4;

// Async global->LDS direct copy, 16B per lane. LDS dest must be
// wave-uniform base + lane*16 (our staging layouts satisfy this: tid*16B).
#define GLOAD_LDS16(gp, lp)                                                   \
    __builtin_amdgcn_global_load_lds(                                         \
        (const __attribute__((address_space(1))) unsigned int*)(gp),          \
        (__attribute__((address_space(3))) unsigned int*)(lp), 16, 0, 0)

// ---------------------------------------------------------------------------
// Weight prep: cast fp32 W[l][h][512][1024] -> fp16 Wt[mat][1024][512]
// (transposed so B-operand fragments are contiguous 16B runs in k).
// mat index = (l*2 + dir)*2 + h
// R3: 32x32 LDS transpose tiles. The old version read src with 4KB stride
// (1 float per 64B line, latency-bound). Now both global sides are coalesced;
// LDS pad +1 breaks read-phase bank conflicts.
// fp16 (not bf16): bf16 GEMM rounding amplified via sigmoid-gate * large-x
// gave absmax 4.5 > 1.68 (R1); fp16 cuts input rounding 8x -> 0.64 (R2).
// ---------------------------------------------------------------------------
__global__ __launch_bounds__(256) void prep_w_kernel(
    const float* __restrict__ fwW, const float* __restrict__ bwW,
    _Float16* __restrict__ Wt)
{
    __shared__ float tile[32][33];
    int bid = blockIdx.x;            // 8 mats * 16 k-tiles * 32 n-tiles = 4096
    int mat = bid >> 9;
    int t   = bid & 511;
    int kt  = t >> 5;                // 0..15  (k-tile)
    int nt  = t & 31;                // 0..31  (n-tile)
    int l   = mat >> 2;
    int dir = (mat >> 1) & 1;
    int h   = mat & 1;
    const float* src = (dir ? bwW : fwW) + (long long)(l * 2 + h) * (512LL * 1024);

    int tx = threadIdx.x & 31;       // fast dim (coalesced)
    int ty = threadIdx.x >> 5;       // 0..7
#pragma unroll
    for (int j = 0; j < 4; ++j) {
        int k = kt * 32 + ty + j * 8;
        tile[ty + j * 8][tx] = src[(long long)k * 1024 + nt * 32 + tx];
    }
    __syncthreads();
    _Float16* dst = Wt + (long long)mat * (1024LL * 512);
#pragma unroll
    for (int j = 0; j < 4; ++j) {
        int n = nt * 32 + ty + j * 8;
        // value = src[kt*32+tx][n] = tile[tx][ty+j*8]; bank = (33*tx+c)%32 -> distinct
        dst[(long long)n * 512 + kt * 32 + tx] = (_Float16)tile[tx][ty + j * 8];
    }
}

// ---------------------------------------------------------------------------
// Band conv along S. causal: y[t] = sum_e w[e]*x[t-16+e]; anticausal:
// y[t] = sum_e w[e]*x[t+e]. Unified: buf[i] = x[t0 + i - (causal?16:0)].
// 4 outputs per thread (20 loads -> 4 outputs). fp16 output only (R2).
// Streaming, no reuse across blocks beyond L2's natural capture -> unchanged.
// ---------------------------------------------------------------------------
__global__ __launch_bounds__(256) void band_conv_kernel(
    const float* __restrict__ src, long long bstride, int rstride,
    const float* __restrict__ w17, int causal,
    _Float16* __restrict__ Th)
{
    int id = blockIdx.x * 256 + threadIdx.x;  // B * (S/4) * D threads
    int c  = id & (D_ - 1);
    int tt = (id >> 9) & (S_ / 4 - 1);
    int b  = id >> 18;
    int t0 = tt * 4;

    float w[17];
#pragma unroll
    for (int e = 0; e < 17; ++e) w[e] = w17[e];

    float buf[20];
    int tbase = t0 - (causal ? 16 : 0);
    const float* sp = src + (long long)b * bstride + c;
#pragma unroll
    for (int i = 0; i < 20; ++i) {
        int t = tbase + i;
        buf[i] = (t >= 0 && t < S_) ? sp[(long long)t * rstride] : 0.f;
    }
#pragma unroll
    for (int j = 0; j < 4; ++j) {
        float a = 0.f;
#pragma unroll
        for (int e = 0; e <= 16; ++e) a = fmaf(w[e], buf[j + e], a);
        Th[((long long)(b * S_ + t0 + j)) * D_ + c] = (_Float16)a;
    }
}

// ---------------------------------------------------------------------------
// One highway iteration, fused: proj = X(fp16) @ W(fp16) + b, then
// out = sigmoid(gate)*x + (1-sigmoid(gate))*relu(nonlinear).
// Block: 128 M-rows x 64 output cols; computes BOTH proj halves so the
// epilogue fuses in-register. 4 waves: wave&1 -> M half, wave>>1 -> 32-col half.
//
// R3 changes:
//  * 1-D grid 2048 with XCD-chunked swizzle, col-block FASTEST in logical
//    order: the 8 col-blocks sharing an A row-panel are co-resident on one
//    XCD -> A staged re-reads (7/8 of 512MB total staging) become L2 hits
//    instead of L3 traffic. (T1; nwg%8==0 so the simple form is bijective.)
//  * Double-buffered LDS, prefetch-before-compute (T3 minimum 2-phase):
//    one barrier per K-step, next-tile global_load_lds latency hides under
//    current tile's ds_read+MFMA.
//  * Epilogue x-tile restaged through LDS with 4 coalesced global_load_lds
//    (reuses the As buffers) instead of 32 scattered 2B global loads/thread.
//
// MFMA 16x16x32 f16; verified layouts (dtype-independent on gfx950):
//   A frag: A[m=lane&15][k=quad*8+j]; B frag: B[k=quad*8+j][n=lane&15]
//   C/D:    row(m)=quad*4+reg, col(n)=lane&15
// ---------------------------------------------------------------------------
__global__ __launch_bounds__(256) void hw_step_kernel(
    const _Float16* __restrict__ Xh,         // [M][512] fp16 GEMM + x input
    const _Float16* __restrict__ Wt,         // [1024][512] fp16 (k-contig)
    const float* __restrict__ bias,          // [1024]
    float* __restrict__ outF, int outF_stride,  // may be null
    _Float16* __restrict__ outH)                // may be null
{
    // [2 buffers][128 rows][32 k] fp16 each; flat so the epilogue x-tile
    // (16KB) can span both A buffers.
    __shared__ _Float16 As[2 * 128 * 32];
    __shared__ _Float16 Bs[2 * 128 * 32];

    int tid = threadIdx.x;

    // XCD-chunked swizzle (2048 blocks, 8 XCDs, hardware id round-robins
    // f%8 across XCDs): XCD k gets logical ids [256k, 256k+256) = 32
    // contiguous row-panels x all 8 col-blocks, col fastest.
    int f = blockIdx.x;
    int L = (f & 7) * 256 + (f >> 3);
    int colb = L & 7;
    int rowb = L >> 3;
    long long m0 = (long long)rowb * 128;
    int n0   = colb * 64;

    int lane = tid & 63;
    int wave = tid >> 6;
    int wm   = (wave & 1) * 64;
    int wn   = (wave >> 1) * 32;
    int ln   = lane & 15;
    int q    = lane >> 4;

    f32x4 acc[2][2][4];
#pragma unroll
    for (int h = 0; h < 2; ++h)
#pragma unroll
        for (int jn = 0; jn < 2; ++jn)
#pragma unroll
            for (int i = 0; i < 4; ++i) acc[h][jn][i] = (f32x4){0.f, 0.f, 0.f, 0.f};

    int srow = tid >> 2;        // 0..63
    int scol = (tid & 3) * 8;   // fp16 offset in 32-wide k row
    const _Float16* gA0 = Xh + (m0 + srow) * 512 + scol;
    const _Float16* gA1 = gA0 + 64 * 512;
    const _Float16* gB0 = Wt + (long long)(n0 + srow) * 512 + scol;
    const _Float16* gB1 = gB0 + 512 * 512;

    // Stage K-tile k0 into buffer b. LDS dest = buffer base + tid*16B:
    // wave-uniform base + lane*16B, as global_load_lds requires.
    auto stage = [&](int b, int k0) {
        _Float16* lA = &As[b * 4096 + tid * 8];
        _Float16* lB = &Bs[b * 4096 + tid * 8];
        GLOAD_LDS16(gA0 + k0, lA);
        GLOAD_LDS16(gA1 + k0, lA + 64 * 32);
        GLOAD_LDS16(gB0 + k0, lB);
        GLOAD_LDS16(gB1 + k0, lB + 64 * 32);
    };

    auto compute = [&](int b) {
        const _Float16* Ab = &As[b * 4096];
        const _Float16* Bb = &Bs[b * 4096];
        f16x8 af[4];
#pragma unroll
        for (int i = 0; i < 4; ++i)
            af[i] = *(const f16x8*)&Ab[(wm + i * 16 + ln) * 32 + q * 8];
        f16x8 bfr[2][2];
#pragma unroll
        for (int h = 0; h < 2; ++h)
#pragma unroll
            for (int jn = 0; jn < 2; ++jn)
                bfr[h][jn] = *(const f16x8*)&Bb[(h * 64 + wn + jn * 16 + ln) * 32 + q * 8];
#pragma unroll
        for (int h = 0; h < 2; ++h)
#pragma unroll
            for (int jn = 0; jn < 2; ++jn)
#pragma unroll
                for (int i = 0; i < 4; ++i)
                    acc[h][jn][i] = __builtin_amdgcn_mfma_f32_16x16x32_f16(
                        af[i], bfr[h][jn], acc[h][jn][i], 0, 0, 0);
    };

    // 2-phase pipeline: prefetch tile t+1, compute tile t, single barrier.
    // Barrier N guarantees (a) prefetch into cur^1 landed (compiler emits
    // s_waitcnt vmcnt(0) before s_barrier) and (b) all waves finished
    // reading cur -> iter N+1 may overwrite it. Race-free per T3 template.
    stage(0, 0);
    __syncthreads();
    int cur = 0;
    for (int k0 = 32; k0 < 512; k0 += 32) {
        stage(cur ^ 1, k0);
        compute(cur);
        __syncthreads();
        cur ^= 1;
    }
    compute(cur);

    // ---- Epilogue: restage x-tile Xh[m0..m0+128)[n0..n0+64) (16KB fp16)
    // into the As area with 4 coalesced global_load_lds (the source panel is
    // L2-hot: it is a k-slice of the A panel this XCD just staged).
    __syncthreads();   // all waves done reading As
    {
        int xrow = tid >> 3;              // 0..31
        int xcol = (tid & 7) * 8;         // 0,8,..,56
        const _Float16* gx = Xh + (m0 + xrow) * 512 + n0 + xcol;
#pragma unroll
        for (int j = 0; j < 4; ++j)
            GLOAD_LDS16(gx + (long long)j * 32 * 512, &As[j * 2048 + tid * 8]);
    }
    __syncthreads();   // vmcnt(0) drained before barrier

    // Fused highway epilogue; x read from LDS (Xs[row][col], row-major 64-wide)
#pragma unroll
    for (int jn = 0; jn < 2; ++jn) {
        int c  = n0 + wn + jn * 16 + ln;   // 0..511
        int xc = wn + jn * 16 + ln;
        float bnl = bias[c];
        float bg  = bias[512 + c];
#pragma unroll
        for (int i = 0; i < 4; ++i) {
#pragma unroll
            for (int r = 0; r < 4; ++r) {
                int xr = wm + i * 16 + q * 4 + r;
                long long m = m0 + xr;
                float nl = acc[0][jn][i][r] + bnl;
                float gt = acc[1][jn][i][r] + bg;
                float g  = 1.f / (1.f + __expf(-gt));
                float xv = (float)As[xr * 64 + xc];
                float o  = g * xv + (1.f - g) * fmaxf(nl, 0.f);
                if (outF) outF[m * (long long)outF_stride + c] = o;
                if (outH) outH[m * 512 + c] = (_Float16)o;
            }
        }
    }
}

// ---------------------------------------------------------------------------
extern "C" void kernel_launch(void* const* d_in, const int* in_sizes, int n_in,
                              void* d_out, int out_size, void* d_ws, size_t ws_size,
                              hipStream_t stream)
{
    const float* inputs  = (const float*)d_in[0];
    // d_in[1] = masks: all ones, unused by the reference
    const float* fw_band = (const float*)d_in[2];
    const float* bw_band = (const float*)d_in[3];
    const float* fw_W    = (const float*)d_in[4];
    const float* fw_b    = (const float*)d_in[5];
    const float* bw_W    = (const float*)d_in[6];
    const float* bw_b    = (const float*)d_in[7];
    float* out = (float*)d_out;  // [2][16][2048][1024]

    char* ws = (char*)d_ws;
    const size_t SZ_TH = (size_t)M_ * D_ * 2;    // 32 MB fp16 activation
    _Float16* Th = (_Float16*)(ws);
    _Float16* Hh = (_Float16*)(ws + SZ_TH);
    _Float16* Wt = (_Float16*)(ws + 2 * SZ_TH);  // 8 MB fp16 weights

    prep_w_kernel<<<4096, 256, 0, stream>>>(fw_W, bw_W, Wt);

    for (int l = 0; l < 2; ++l) {
        for (int dir = 0; dir < 2; ++dir) {
            const float* src; long long bstride; int rstride;
            if (l == 0) { src = inputs; bstride = (long long)S_ * D_; rstride = D_; }
            else {
                src = out + (long long)(l - 1) * M_ * 1024 + dir * 512;
                bstride = (long long)S_ * 1024; rstride = 1024;
            }
            const float* band = (dir ? bw_band : fw_band) + l * 17;
            band_conv_kernel<<<(B_ * (S_ / 4) * D_) / 256, 256, 0, stream>>>(
                src, bstride, rstride, band, dir == 0 ? 1 : 0, Th);

            const _Float16* W0 = Wt + (size_t)((l * 2 + dir) * 2 + 0) * (1024 * 512);
            const _Float16* W1 = Wt + (size_t)((l * 2 + dir) * 2 + 1) * (1024 * 512);
            const float* bias = (dir ? bw_b : fw_b) + (size_t)(l * 2) * 1024;

            // highway iter 0: Th -> Hh
            hw_step_kernel<<<2048, 256, 0, stream>>>(Th, W0, bias, nullptr, 0, Hh);
            // highway iter 1: Hh -> d_out slice (fp32, stride 1024)
            float* oF = out + (long long)l * M_ * 1024 + dir * 512;
            hw_step_kernel<<<2048, 256, 0, stream>>>(Hh, W1, bias + 1024, oF, 1024, nullptr);
        }
    }
}

// Round 2
// 821.269 us; speedup vs baseline: 1.3222x; 1.0862x over previous
//
#include <hip/hip_runtime.h>
#include <hip/hip_bf16.h>

#define B_ 16
#define S_ 2048
#define D_ 512
#define M_ (B_ * S_)  // 32768 rows for the GEMMs

typedef __attribute__((ext_vector_type(8))) _Float16 f16x8;
typedef __attribute__((ext_vector_type(4))) float f32x4;

// Async global->LDS direct copy, 16B per lane. LDS dest must be
// wave-uniform base + lane*16 (our staging layouts satisfy this: tid*16B).
#define GLOAD_LDS16(gp, lp)                                                   \
    __builtin_amdgcn_global_load_lds(                                         \
        (const __attribute__((address_space(1))) unsigned int*)(gp),          \
        (__attribute__((address_space(3))) unsigned int*)(lp), 16, 0, 0)

// ---------------------------------------------------------------------------
// Weight prep: cast fp32 W[l][h][512][1024] -> fp16 Wt[mat][1024][512]
// (transposed so B-operand fragments are contiguous 16B runs in k).
// 32x32 LDS transpose tiles, both global sides coalesced (R3).
// fp16 (not bf16): bf16 GEMM rounding amplified via sigmoid-gate * large-x
// gave absmax 4.5 > 1.68 (R1); fp16 cuts input rounding 8x -> 0.64 (R2).
// ---------------------------------------------------------------------------
__global__ __launch_bounds__(256) void prep_w_kernel(
    const float* __restrict__ fwW, const float* __restrict__ bwW,
    _Float16* __restrict__ Wt)
{
    __shared__ float tile[32][33];
    int bid = blockIdx.x;            // 8 mats * 16 k-tiles * 32 n-tiles = 4096
    int mat = bid >> 9;
    int t   = bid & 511;
    int kt  = t >> 5;                // 0..15  (k-tile)
    int nt  = t & 31;                // 0..31  (n-tile)
    int l   = mat >> 2;
    int dir = (mat >> 1) & 1;
    int h   = mat & 1;
    const float* src = (dir ? bwW : fwW) + (long long)(l * 2 + h) * (512LL * 1024);

    int tx = threadIdx.x & 31;       // fast dim (coalesced)
    int ty = threadIdx.x >> 5;       // 0..7
#pragma unroll
    for (int j = 0; j < 4; ++j) {
        int k = kt * 32 + ty + j * 8;
        tile[ty + j * 8][tx] = src[(long long)k * 1024 + nt * 32 + tx];
    }
    __syncthreads();
    _Float16* dst = Wt + (long long)mat * (1024LL * 512);
#pragma unroll
    for (int j = 0; j < 4; ++j) {
        int n = nt * 32 + ty + j * 8;
        dst[(long long)n * 512 + kt * 32 + tx] = (_Float16)tile[tx][ty + j * 8];
    }
}

// ---------------------------------------------------------------------------
// Band conv along S (unchanged; ~at BW roofline for its size).
// ---------------------------------------------------------------------------
__global__ __launch_bounds__(256) void band_conv_kernel(
    const float* __restrict__ src, long long bstride, int rstride,
    const float* __restrict__ w17, int causal,
    _Float16* __restrict__ Th)
{
    int id = blockIdx.x * 256 + threadIdx.x;  // B * (S/4) * D threads
    int c  = id & (D_ - 1);
    int tt = (id >> 9) & (S_ / 4 - 1);
    int b  = id >> 18;
    int t0 = tt * 4;

    float w[17];
#pragma unroll
    for (int e = 0; e < 17; ++e) w[e] = w17[e];

    float buf[20];
    int tbase = t0 - (causal ? 16 : 0);
    const float* sp = src + (long long)b * bstride + c;
#pragma unroll
    for (int i = 0; i < 20; ++i) {
        int t = tbase + i;
        buf[i] = (t >= 0 && t < S_) ? sp[(long long)t * rstride] : 0.f;
    }
#pragma unroll
    for (int j = 0; j < 4; ++j) {
        float a = 0.f;
#pragma unroll
        for (int e = 0; e <= 16; ++e) a = fmaf(w[e], buf[j + e], a);
        Th[((long long)(b * S_ + t0 + j)) * D_ + c] = (_Float16)a;
    }
}

// ---------------------------------------------------------------------------
// One highway iteration, fused: proj = X(fp16) @ W(fp16) + b, then
// out = sigmoid(gate)*x + (1-sigmoid(gate))*relu(nonlinear).
//
// R4: 8-phase-class deep pipeline (T3+T4 counted vmcnt, gating T2 swizzle +
// T5 setprio), per the measured regime-gate (2-phase critical path is the
// stage+vmcnt0+barrier drain; T2/T5 null without the counted schedule).
//
// Geometry: BM=256 rows x 128 out cols (256 proj cols: nonlinear + gate),
// BK=64, 8 K-tiles (K=512), 512 threads = 8 waves (4 M-waves x 2 N-waves).
// LDS 128KB: A[2buf][256][64] fp16 + B[2buf][256][64] fp16 (B local rows
// 0-127 = nonlinear cols, 128-255 = gate cols). 1 block/CU.
//
// Per K-tile: 4 phases = (h = p&1: B-half) x (ks = p>>1: k-half).
// Phase: {ds_read frags; stage one half-tile; [p3: s_waitcnt vmcnt(2)];
//         s_barrier; lgkmcnt(0); setprio(1); 16 MFMA; setprio(0); s_barrier}.
// Stage schedule (race-analyzed against last-use phases):
//   p0: Alo(kt+1)->buf^1   (Alo(kt-1) dead since kt-1 end)
//   p1: Ahi(kt+1)->buf^1
//   p2: Bhi(kt+1)->buf^1   (Bhi(kt-1) dead since kt-1 p3)
//   p3: Blo(kt+2)->buf     (Blo(kt) dead after p2; p2 trailing barrier orders)
// vmcnt(2) at p3 => all but the 2 newest loads (= Blo(kt+2)) landed =>
// kt+1's Alo/Ahi/Bhi (staged p0-p2) + Blo(kt+1) (staged kt-1 p3) are in LDS.
// Loads thus stay in flight ACROSS barriers; vmcnt never drains to 0 in the
// main loop (kt==6 drains as epilogue-of-pipeline).
//
// T2 swizzle: LDS byte = row*128 + (colbyte ^ ((row&7)<<4)); applied on the
// ds_read address AND pre-permuted on the global source (rule 21: the
// global_load_lds dest stays linear lane*16).
//
// MFMA 16x16x32 f16; verified layouts (dtype-independent on gfx950):
//   A frag: A[m=lane&15][k=q*8+j]; B frag: B[k=q*8+j][n=lane&15]
//   C/D:    row(m)=q*4+reg, col(n)=lane&15
// K-accumulation order (k ascending in 32-steps) identical to R3 ->
// bitwise-identical results, absmax stays 0.71875.
// ---------------------------------------------------------------------------
__global__ __launch_bounds__(512, 2) void hw_step_kernel(
    const _Float16* __restrict__ Xh,         // [M][512] fp16 GEMM + x input
    const _Float16* __restrict__ Wt,         // [1024][512] fp16 (k-contig)
    const float* __restrict__ bias,          // [1024]
    float* __restrict__ outF, int outF_stride,  // may be null
    _Float16* __restrict__ outH)                // may be null
{
    __shared__ _Float16 lds[65536];   // 128KB: A at byte 0, B at byte 65536
    char* ldsb = (char*)lds;

    int tid = threadIdx.x;

    // XCD-chunked swizzle: 512 blocks, 64/XCD, col-block fastest within chunk
    // -> the 4 col-blocks sharing an A row-panel co-reside on one XCD L2.
    int f = blockIdx.x;
    int L = (f & 7) * 64 + (f >> 3);
    int colb = L & 3;                 // 0..3
    int rowb = L >> 2;                // 0..127
    long long m0 = (long long)rowb * 256;
    int n0 = colb * 128;              // output-column base (0..511 space)

    int lane = tid & 63;
    int wave = tid >> 6;
    int wave_m = wave >> 1;           // 0..3 -> 64 rows each
    int wave_n = wave & 1;            // 0..1 -> 64 out cols each
    int wrow = wave_m * 64;
    int wn   = wave_n * 64;
    int ln = lane & 15;
    int q  = lane >> 4;

    // ---- staging constants: thread t stages LDS slot (j*512+t)*16 of a
    // 16KB half-tile (128 rows x 128B). Local row = j*64 + (t>>3); the
    // source column is pre-permuted so the linear LDS write realizes the
    // XOR-swizzled layout: col_fp16 = kt*64 + 8*((t&7) ^ (row&7)).
    int rloc  = tid >> 3;                         // 0..63
    int cperm = 8 * ((tid & 7) ^ (rloc & 7));     // fp16 units, 16B-aligned
    const _Float16* gA  = Xh + (m0 + rloc) * 512 + cperm;
    const _Float16* gBn = Wt + (long long)(n0 + rloc) * 512 + cperm;
    const _Float16* gBg = Wt + (long long)(512 + n0 + rloc) * 512 + cperm;

    // half-tile stage: b=buffer, kt=K-tile, h2=half (A: row-half, B: nl/gate)
    auto stageA = [&](int b, int kt, int h2) {
#pragma unroll
        for (int j = 0; j < 2; ++j)
            GLOAD_LDS16(gA + (long long)(h2 * 128 + j * 64) * 512 + kt * 64,
                        ldsb + b * 32768 + h2 * 16384 + (j * 512 + tid) * 16);
    };
    auto stageB = [&](int b, int kt, int h2) {
        const _Float16* g = h2 ? gBg : gBn;
#pragma unroll
        for (int j = 0; j < 2; ++j)
            GLOAD_LDS16(g + (long long)(j * 64) * 512 + kt * 64,
                        ldsb + 65536 + b * 32768 + h2 * 16384 + (j * 512 + tid) * 16);
    };

    f32x4 acc[2][4][4];   // [h][jn][i]
#pragma unroll
    for (int h = 0; h < 2; ++h)
#pragma unroll
        for (int jn = 0; jn < 4; ++jn)
#pragma unroll
            for (int i = 0; i < 4; ++i) acc[h][jn][i] = (f32x4){0.f, 0.f, 0.f, 0.f};

    // ---- prologue: K-tile0 complete + Blo(1); vmcnt(2) leaves Blo(1) in flight
    stageB(0, 0, 0);
    stageA(0, 0, 0);
    stageA(0, 0, 1);
    stageB(0, 0, 1);
    stageB(1, 1, 0);
    asm volatile("s_waitcnt vmcnt(2)" ::: "memory");
    __builtin_amdgcn_s_barrier();

    f16x8 af[4];
    for (int kt = 0; kt < 8; ++kt) {
        int b = kt & 1;
        const char* Ab = ldsb + b * 32768;
        const char* Bb = ldsb + 65536 + b * 32768;
#pragma unroll
        for (int p = 0; p < 4; ++p) {
            const int h = p & 1, ks = p >> 1;
            const int cb = ks * 64 + q * 16;   // colbyte before swizzle
            // ds_read register subtiles (A reused across the two h-phases)
            if ((p & 1) == 0) {
#pragma unroll
                for (int i = 0; i < 4; ++i) {
                    int row = wrow + i * 16 + ln;
                    af[i] = *(const f16x8*)(Ab + row * 128 + (cb ^ ((row & 7) << 4)));
                }
            }
            f16x8 bf[4];
#pragma unroll
            for (int jn = 0; jn < 4; ++jn) {
                int row = h * 128 + wn + jn * 16 + ln;
                bf[jn] = *(const f16x8*)(Bb + row * 128 + (cb ^ ((row & 7) << 4)));
            }
            // stage (counted-vmcnt pipeline; see schedule above)
            if (p == 0) { if (kt + 1 < 8) stageA(b ^ 1, kt + 1, 0); }
            if (p == 1) { if (kt + 1 < 8) stageA(b ^ 1, kt + 1, 1); }
            if (p == 2) { if (kt + 1 < 8) stageB(b ^ 1, kt + 1, 1); }
            if (p == 3) {
                if (kt + 2 < 8) stageB(b, kt + 2, 0);
                if (kt < 6)       asm volatile("s_waitcnt vmcnt(2)" ::: "memory");
                else if (kt == 6) asm volatile("s_waitcnt vmcnt(0)" ::: "memory");
            }
            __builtin_amdgcn_s_barrier();
            asm volatile("s_waitcnt lgkmcnt(0)" ::: "memory");
            __builtin_amdgcn_sched_barrier(0);
            __builtin_amdgcn_s_setprio(1);
#pragma unroll
            for (int jn = 0; jn < 4; ++jn)
#pragma unroll
                for (int i = 0; i < 4; ++i)
                    acc[h][jn][i] = __builtin_amdgcn_mfma_f32_16x16x32_f16(
                        af[i], bf[jn], acc[h][jn][i], 0, 0, 0);
            __builtin_amdgcn_s_setprio(0);
            __builtin_amdgcn_s_barrier();
        }
    }

    // ---- Epilogue: restage x-tile Xh[m0..+256)[n0..+128) (64KB fp16) into
    // the A region with 8 coalesced global_load_lds (source is L2-hot: it is
    // a column-slice of the A panel this XCD just streamed). Linear layout
    // [256][128] fp16; minor read conflicts are negligible vs the K-loop.
#pragma unroll
    for (int j = 0; j < 8; ++j) {
        int idx = j * 512 + tid;
        int row = idx >> 4;               // 0..255
        int col = (idx & 15) * 8;         // fp16 col 0..120
        GLOAD_LDS16(Xh + (m0 + row) * 512 + n0 + col, ldsb + idx * 16);
    }
    asm volatile("s_waitcnt vmcnt(0)" ::: "memory");
    __builtin_amdgcn_s_barrier();

#pragma unroll
    for (int jn = 0; jn < 4; ++jn) {
        int oc = wn + jn * 16 + ln;       // 0..127 local out col
        int c  = n0 + oc;                 // 0..511
        float bnl = bias[c];
        float bg  = bias[512 + c];
#pragma unroll
        for (int i = 0; i < 4; ++i) {
#pragma unroll
            for (int r = 0; r < 4; ++r) {
                int xr = wrow + i * 16 + q * 4 + r;
                long long m = m0 + xr;
                float nl = acc[0][jn][i][r] + bnl;
                float gt = acc[1][jn][i][r] + bg;
                float g  = 1.f / (1.f + __expf(-gt));
                float xv = (float)lds[xr * 128 + oc];
                float o  = g * xv + (1.f - g) * fmaxf(nl, 0.f);
                if (outF) outF[m * (long long)outF_stride + c] = o;
                if (outH) outH[m * 512 + c] = (_Float16)o;
            }
        }
    }
}

// ---------------------------------------------------------------------------
extern "C" void kernel_launch(void* const* d_in, const int* in_sizes, int n_in,
                              void* d_out, int out_size, void* d_ws, size_t ws_size,
                              hipStream_t stream)
{
    const float* inputs  = (const float*)d_in[0];
    // d_in[1] = masks: all ones, unused by the reference
    const float* fw_band = (const float*)d_in[2];
    const float* bw_band = (const float*)d_in[3];
    const float* fw_W    = (const float*)d_in[4];
    const float* fw_b    = (const float*)d_in[5];
    const float* bw_W    = (const float*)d_in[6];
    const float* bw_b    = (const float*)d_in[7];
    float* out = (float*)d_out;  // [2][16][2048][1024]

    char* ws = (char*)d_ws;
    const size_t SZ_TH = (size_t)M_ * D_ * 2;    // 32 MB fp16 activation
    _Float16* Th = (_Float16*)(ws);
    _Float16* Hh = (_Float16*)(ws + SZ_TH);
    _Float16* Wt = (_Float16*)(ws + 2 * SZ_TH);  // 8 MB fp16 weights

    prep_w_kernel<<<4096, 256, 0, stream>>>(fw_W, bw_W, Wt);

    for (int l = 0; l < 2; ++l) {
        for (int dir = 0; dir < 2; ++dir) {
            const float* src; long long bstride; int rstride;
            if (l == 0) { src = inputs; bstride = (long long)S_ * D_; rstride = D_; }
            else {
                src = out + (long long)(l - 1) * M_ * 1024 + dir * 512;
                bstride = (long long)S_ * 1024; rstride = 1024;
            }
            const float* band = (dir ? bw_band : fw_band) + l * 17;
            band_conv_kernel<<<(B_ * (S_ / 4) * D_) / 256, 256, 0, stream>>>(
                src, bstride, rstride, band, dir == 0 ? 1 : 0, Th);

            const _Float16* W0 = Wt + (size_t)((l * 2 + dir) * 2 + 0) * (1024 * 512);
            const _Float16* W1 = Wt + (size_t)((l * 2 + dir) * 2 + 1) * (1024 * 512);
            const float* bias = (dir ? bw_b : fw_b) + (size_t)(l * 2) * 1024;

            // highway iter 0: Th -> Hh
            hw_step_kernel<<<512, 512, 0, stream>>>(Th, W0, bias, nullptr, 0, Hh);
            // highway iter 1: Hh -> d_out slice (fp32, stride 1024)
            float* oF = out + (long long)l * M_ * 1024 + dir * 512;
            hw_step_kernel<<<512, 512, 0, stream>>>(Hh, W1, bias + 1024, oF, 1024, nullptr);
        }
    }
}